// Round 1
// baseline (3089.510 us; speedup 1.0000x reference)
//
#include <hip/hip_runtime.h>
#include <hip/hip_fp16.h>

typedef _Float16 f16;
typedef _Float16 f16x8 __attribute__((ext_vector_type(8)));
typedef _Float16 f16x4 __attribute__((ext_vector_type(4)));
typedef float    f32x4 __attribute__((ext_vector_type(4)));

#define NB   8
#define NN   32
#define NT   64
#define ND   64
#define NK   4
#define NH   256
#define NSO  256
#define NE   992
#define TOUT 63
#define M1   (NB*TOUT*NN)   // 16128 node-time rows

// ---- workspace layout (bytes) ----
static constexpr size_t SZ_RS   = (size_t)M1 * 1024 * 2;        // 33,030,144 (f16, [m][k*256+h])
static constexpr size_t OFF_R   = 0;
static constexpr size_t OFF_S   = OFF_R + SZ_RS;
static constexpr size_t OFF_W2T = OFF_S + SZ_RS;                // f16 [k][co][h]   524,288
static constexpr size_t OFF_WF1 = OFF_W2T + 4*256*256*2;        // f16 [co][d(320)] 163,840
static constexpr size_t OFF_WF2 = OFF_WF1 + 256*320*2;          // f16 [co][h]      131,072
static constexpr size_t OFF_WF3 = OFF_WF2 + 256*256*2;          // f16 [d][h]        32,768
static constexpr size_t OFF_REL = OFF_WF3 + 64*256*2;           // f32 [b][ns][k][32] 131,072
static constexpr size_t OFF_AGG = OFF_REL + (size_t)NB*NN*NK*32*4; // f32 [m][256]  16,515,072
// total = 83,558,400 bytes

// ============================ K0: weight prep ============================
__global__ __launch_bounds__(256) void k0_prep(
    const float* __restrict__ W2, const float* __restrict__ Wf1,
    const float* __restrict__ Wf2, const float* __restrict__ Wf3,
    const float* __restrict__ rel,
    f16* __restrict__ W2T, f16* __restrict__ Wf1T, f16* __restrict__ Wf2T,
    f16* __restrict__ Wf3T, float* __restrict__ REL)
{
    int id = blockIdx.x * 256 + threadIdx.x;
    if (id < 262144) {                      // W2T[k][co][h] = W2[k][h][co]
        int k = id >> 16, co = (id >> 8) & 255, h = id & 255;
        W2T[id] = (f16)W2[k*65536 + h*256 + co];
    } else if (id < 344064) {               // Wf1T[co][d] = Wf1[d][co], d<320
        int i = id - 262144; int co = i / 320, d = i % 320;
        Wf1T[i] = (f16)Wf1[d*256 + co];
    } else if (id < 409600) {               // Wf2T[co][h] = Wf2[h][co]
        int i = id - 344064; int co = i >> 8, h = i & 255;
        Wf2T[i] = (f16)Wf2[h*256 + co];
    } else if (id < 425984) {               // Wf3T[d][h] = Wf3[h][d], d<64
        int i = id - 409600; int d = i >> 8, h = i & 255;
        Wf3T[i] = (f16)Wf3[h*64 + d];
    } else {                                // REL[b][ns][k][j], self-edge -> 0
        int i = id - 425984;
        int j = i & 31, k = (i >> 5) & 3, ns = (i >> 7) & 31, b = i >> 12;
        float v = 0.f;
        if (j != ns) v = rel[(b*NE + ns*31 + (j < ns ? j : j - 1))*NK + k];
        REL[i] = v;
    }
}

// ============ K1: per-node layer-1 partials R,S (fp32 GEMM -> f16) ============
// R[m][k*256+h] = x_m @ W1[k][0:64];  S[m][k*256+h] = x_m @ W1[k][64:128] + b1[k]
__global__ __launch_bounds__(256) void k1_partials(
    const float* __restrict__ inputs, const float* __restrict__ W1,
    const float* __restrict__ b1, f16* __restrict__ Rb, f16* __restrict__ Sb)
{
    __shared__ __align__(16) float xT[64][68];   // [d][row]
    __shared__ __align__(16) float Wl[64][68];   // [d][col]
    int tid = threadIdx.x;
    int bm = blockIdx.x, cb = blockIdx.y;
    int c0 = cb * 64, k = c0 >> 9, dd = (c0 >> 8) & 1, h0 = c0 & 255;

    for (int it = 0; it < 4; ++it) {       // stage x transposed
        int idx = it*256 + tid;
        int r = idx >> 4, ds = idx & 15;
        int m = bm*64 + r;
        int b = m / 2016, r2 = m % 2016, t = r2 >> 5, n = r2 & 31;
        f32x4 v = *(const f32x4*)&inputs[((b*NN + n)*NT + t)*ND + ds*4];
        xT[ds*4+0][r] = v[0]; xT[ds*4+1][r] = v[1];
        xT[ds*4+2][r] = v[2]; xT[ds*4+3][r] = v[3];
    }
    for (int it = 0; it < 4; ++it) {       // stage W1 sub-block [64][64]
        int idx = it*256 + tid;
        int d = idx >> 4, cl = (idx & 15) * 4;
        f32x4 v = *(const f32x4*)&W1[(k*128 + dd*64 + d)*NH + h0 + cl];
        *(f32x4*)&Wl[d][cl] = v;
    }
    __syncthreads();
    int ty = tid >> 4, tx = tid & 15;
    float acc[4][4] = {};
    for (int d = 0; d < 64; ++d) {
        f32x4 a = *(const f32x4*)&xT[d][ty*4];
        f32x4 w = *(const f32x4*)&Wl[d][tx*4];
        #pragma unroll
        for (int i = 0; i < 4; ++i)
            #pragma unroll
            for (int j = 0; j < 4; ++j) acc[i][j] += a[i] * w[j];
    }
    f16* dst = dd ? Sb : Rb;
    #pragma unroll
    for (int i = 0; i < 4; ++i) {
        size_t m = (size_t)(bm*64 + ty*4 + i);
        f16x4 o;
        #pragma unroll
        for (int j = 0; j < 4; ++j) {
            float v = acc[i][j];
            if (dd) v += b1[k*NH + h0 + tx*4 + j];
            o[j] = (f16)v;
        }
        *(f16x4*)&dst[m*1024 + k*256 + h0 + tx*4] = o;
    }
}

// ============ K2: fused edge MLP layer-2 + mixture + sender-aggregate ============
// wg = (b, ns, tc): 4 time steps x 32 padded edges (M=128 rows), 512 threads.
// waves: 2 M-groups x 4 N-groups; per wave 4 Mtiles x 4 Ntiles (acc 64 VGPR/lane).
__global__ __launch_bounds__(512, 4) void k2_edge(
    const f16* __restrict__ Rb, const f16* __restrict__ Sb,
    const f16* __restrict__ W2T, const float* __restrict__ b2,
    const float* __restrict__ REL, float* __restrict__ AGG)
{
    __shared__ __align__(16) f16 h1c[128][72];   // h1 chunk (64 h), +8 pad
    __shared__ __align__(16) f16 w2c[256][72];   // W2^T chunk [co][64 h]
    __shared__ __align__(16) float agg_s[4][256];
    int tid = threadIdx.x;
    int blk = blockIdx.x;
    int ns = blk & 31, tcv = (blk >> 5) & 15, b = blk >> 9;
    int w = tid >> 6, lane = tid & 63, ln = lane & 15, q = lane >> 4;
    int mg = w >> 2, ng = w & 3;

    agg_s[tid >> 8][tid & 255] = 0.f;
    agg_s[2 + (tid >> 8)][tid & 255] = 0.f;

    const f32x4 z4 = {0.f, 0.f, 0.f, 0.f};
    f32x4 acc[4][4];
    for (int k = 0; k < 4; ++k) {
        #pragma unroll
        for (int mt = 0; mt < 4; ++mt)
            #pragma unroll
            for (int nt = 0; nt < 4; ++nt) acc[mt][nt] = z4;

        for (int hc = 0; hc < 4; ++hc) {
            __syncthreads();
            // h1 chunk: relu(R[recv] + S[send]) for 128 rows x 64 h
            #pragma unroll
            for (int it = 0; it < 2; ++it) {
                int idx8 = it*512 + tid;
                int m = idx8 >> 3, seg = idx8 & 7, h = hc*64 + seg*8;
                int t = tcv*4 + (m >> 5); if (t > 62) t = 62;  // clamp pad-t (never stored)
                int j = m & 31;
                size_t base = (size_t)(b*TOUT + t) * NN;
                f16x8 r8 = *(const f16x8*)&Rb[(base + j)*1024 + k*256 + h];
                f16x8 s8 = *(const f16x8*)&Sb[(base + ns)*1024 + k*256 + h];
                f16x8 v;
                #pragma unroll
                for (int e = 0; e < 8; ++e) {
                    f16 x = r8[e] + s8[e];
                    v[e] = x > (f16)0 ? x : (f16)0;
                }
                *(f16x8*)&h1c[m][seg*8] = v;
            }
            // W2^T chunk
            #pragma unroll
            for (int it = 0; it < 4; ++it) {
                int idx8 = it*512 + tid;
                int co = idx8 >> 3, seg = idx8 & 7;
                *(f16x8*)&w2c[co][seg*8] =
                    *(const f16x8*)&W2T[(size_t)(k*256 + co)*256 + hc*64 + seg*8];
            }
            __syncthreads();
            #pragma unroll
            for (int ks = 0; ks < 2; ++ks) {
                f16x8 A[4];
                #pragma unroll
                for (int mt = 0; mt < 4; ++mt)
                    A[mt] = *(const f16x8*)&h1c[mg*64 + mt*16 + ln][ks*32 + q*8];
                #pragma unroll
                for (int nt = 0; nt < 4; ++nt) {
                    f16x8 Bf = *(const f16x8*)&w2c[ng*64 + nt*16 + ln][ks*32 + q*8];
                    #pragma unroll
                    for (int mt = 0; mt < 4; ++mt)
                        acc[mt][nt] = __builtin_amdgcn_mfma_f32_16x16x32_f16(
                            A[mt], Bf, acc[mt][nt], 0, 0, 0);
                }
            }
        }
        // epilogue for mixture k: bias+relu, scale by rel, reduce rows -> agg
        #pragma unroll
        for (int mt = 0; mt < 4; ++mt) {
            int tl = mg*2 + (mt >> 1);
            int e0 = (mt & 1)*16 + q*4;
            f32x4 relv = *(const f32x4*)&REL[((b*NN + ns)*NK + k)*32 + e0];
            #pragma unroll
            for (int nt = 0; nt < 4; ++nt) {
                int co = ng*64 + nt*16 + ln;
                float bias = b2[k*NSO + co];
                float s = 0.f;
                #pragma unroll
                for (int r = 0; r < 4; ++r) {
                    float v = acc[mt][nt][r] + bias;
                    v = v > 0.f ? v : 0.f;
                    s += v * relv[r];
                }
                s += __shfl_xor(s, 16);
                s += __shfl_xor(s, 32);
                if (lane < 16) agg_s[tl][ng*64 + nt*16 + lane] += s;
            }
        }
    }
    __syncthreads();
    #pragma unroll
    for (int it = 0; it < 2; ++it) {
        int idx = it*512 + tid;
        int tl = idx >> 8, co = idx & 255;
        int t = tcv*4 + tl;
        if (t < 63)
            AGG[((size_t)(b*TOUT + t)*NN + ns)*NSO + co] = agg_s[tl][co];
    }
}

// ============ K3: node MLP (320->256->256->64) + residual ============
__global__ __launch_bounds__(256) void k3_node(
    const float* __restrict__ inputs, const float* __restrict__ AGG,
    const f16* __restrict__ Wf1T, const float* __restrict__ bf1,
    const f16* __restrict__ Wf2T, const float* __restrict__ bf2,
    const f16* __restrict__ Wf3T, const float* __restrict__ bf3,
    float* __restrict__ out)
{
    __shared__ __align__(16) f16 aug[64][328];   // [x(64) | agg(256)] + pad
    __shared__ __align__(16) f16 p1[64][264];
    __shared__ __align__(16) f16 wl[256][72];
    int tid = threadIdx.x;
    int w = tid >> 6, lane = tid & 63, ln = lane & 15, q = lane >> 4;
    int m0 = blockIdx.x * 64;

    for (int it = 0; it < 10; ++it) {       // stage aug
        int s = it*256 + tid;
        if (s < 512) {
            int m = s >> 3, hs = s & 7;
            int mrow = m0 + m;
            int b = mrow / 2016, r2 = mrow % 2016, t = r2 >> 5, n = r2 & 31;
            const float* px = &inputs[((b*NN + n)*NT + t)*ND + hs*8];
            f32x4 v0 = *(const f32x4*)px, v1 = *(const f32x4*)(px + 4);
            f16x8 o;
            #pragma unroll
            for (int e = 0; e < 4; ++e) { o[e] = (f16)v0[e]; o[e+4] = (f16)v1[e]; }
            *(f16x8*)&aug[m][hs*8] = o;
        } else {
            int s2 = s - 512;
            int m = s2 >> 5, hs = s2 & 31;
            const float* pa = &AGG[(size_t)(m0 + m)*NSO + hs*8];
            f32x4 v0 = *(const f32x4*)pa, v1 = *(const f32x4*)(pa + 4);
            f16x8 o;
            #pragma unroll
            for (int e = 0; e < 4; ++e) { o[e] = (f16)v0[e]; o[e+4] = (f16)v1[e]; }
            *(f16x8*)&aug[m][64 + hs*8] = o;
        }
    }
    const f32x4 z4 = {0.f, 0.f, 0.f, 0.f};
    // ---- layer 1: K=320 ----
    f32x4 acc1[16];
    #pragma unroll
    for (int nt = 0; nt < 16; ++nt) acc1[nt] = z4;
    for (int hc = 0; hc < 5; ++hc) {
        __syncthreads();
        #pragma unroll
        for (int it = 0; it < 8; ++it) {
            int idx8 = it*256 + tid;
            int co = idx8 >> 3, seg = idx8 & 7;
            *(f16x8*)&wl[co][seg*8] = *(const f16x8*)&Wf1T[co*320 + hc*64 + seg*8];
        }
        __syncthreads();
        #pragma unroll
        for (int ks = 0; ks < 2; ++ks) {
            f16x8 Af = *(const f16x8*)&aug[w*16 + ln][hc*64 + ks*32 + q*8];
            #pragma unroll
            for (int nt = 0; nt < 16; ++nt) {
                f16x8 Bf = *(const f16x8*)&wl[nt*16 + ln][ks*32 + q*8];
                acc1[nt] = __builtin_amdgcn_mfma_f32_16x16x32_f16(Af, Bf, acc1[nt], 0, 0, 0);
            }
        }
    }
    #pragma unroll
    for (int nt = 0; nt < 16; ++nt) {
        int co = nt*16 + ln;
        float bias = bf1[co];
        #pragma unroll
        for (int r = 0; r < 4; ++r) {
            float v = acc1[nt][r] + bias; v = v > 0.f ? v : 0.f;
            p1[w*16 + q*4 + r][co] = (f16)v;
        }
    }
    // ---- layer 2: K=256 ----
    f32x4 acc2[16];
    #pragma unroll
    for (int nt = 0; nt < 16; ++nt) acc2[nt] = z4;
    for (int hc = 0; hc < 4; ++hc) {
        __syncthreads();
        #pragma unroll
        for (int it = 0; it < 8; ++it) {
            int idx8 = it*256 + tid;
            int co = idx8 >> 3, seg = idx8 & 7;
            *(f16x8*)&wl[co][seg*8] = *(const f16x8*)&Wf2T[co*256 + hc*64 + seg*8];
        }
        __syncthreads();
        #pragma unroll
        for (int ks = 0; ks < 2; ++ks) {
            f16x8 Af = *(const f16x8*)&p1[w*16 + ln][hc*64 + ks*32 + q*8];
            #pragma unroll
            for (int nt = 0; nt < 16; ++nt) {
                f16x8 Bf = *(const f16x8*)&wl[nt*16 + ln][ks*32 + q*8];
                acc2[nt] = __builtin_amdgcn_mfma_f32_16x16x32_f16(Af, Bf, acc2[nt], 0, 0, 0);
            }
        }
    }
    f16* p2 = &aug[0][0];    // reuse aug storage, stride 264
    #pragma unroll
    for (int nt = 0; nt < 16; ++nt) {
        int co = nt*16 + ln;
        float bias = bf2[co];
        #pragma unroll
        for (int r = 0; r < 4; ++r) {
            float v = acc2[nt][r] + bias; v = v > 0.f ? v : 0.f;
            p2[(w*16 + q*4 + r)*264 + co] = (f16)v;
        }
    }
    __syncthreads();
    // ---- layer 3: K=256, N=64 ----
    f16* w3 = &wl[0][0];     // reuse wl storage, stride 264
    #pragma unroll
    for (int it = 0; it < 8; ++it) {
        int idx8 = it*256 + tid;
        int d = idx8 >> 5, seg = idx8 & 31;
        *(f16x8*)&w3[d*264 + seg*8] = *(const f16x8*)&Wf3T[d*256 + seg*8];
    }
    __syncthreads();
    f32x4 acc3[4];
    #pragma unroll
    for (int nt = 0; nt < 4; ++nt) acc3[nt] = z4;
    #pragma unroll
    for (int ks = 0; ks < 8; ++ks) {
        f16x8 Af = *(const f16x8*)&p2[(w*16 + ln)*264 + ks*32 + q*8];
        #pragma unroll
        for (int nt = 0; nt < 4; ++nt) {
            f16x8 Bf = *(const f16x8*)&w3[(nt*16 + ln)*264 + ks*32 + q*8];
            acc3[nt] = __builtin_amdgcn_mfma_f32_16x16x32_f16(Af, Bf, acc3[nt], 0, 0, 0);
        }
    }
    #pragma unroll
    for (int nt = 0; nt < 4; ++nt) {
        int d = nt*16 + ln;
        float bias = bf3[d];
        #pragma unroll
        for (int r = 0; r < 4; ++r) {
            int mrow = m0 + w*16 + q*4 + r;
            int b = mrow / 2016, r2 = mrow % 2016, t = r2 >> 5, n = r2 & 31;
            float xv = inputs[((b*NN + n)*NT + t)*ND + d];
            out[((size_t)(b*NN + n)*TOUT + t)*ND + d] = acc3[nt][r] + bias + xv;
        }
    }
}

extern "C" void kernel_launch(void* const* d_in, const int* in_sizes, int n_in,
                              void* d_out, int out_size, void* d_ws, size_t ws_size,
                              hipStream_t stream)
{
    const float* inputs = (const float*)d_in[0];
    const float* rel    = (const float*)d_in[1];
    const float* W1     = (const float*)d_in[4];
    const float* b1     = (const float*)d_in[5];
    const float* W2     = (const float*)d_in[6];
    const float* b2     = (const float*)d_in[7];
    const float* Wf1    = (const float*)d_in[8];
    const float* bf1    = (const float*)d_in[9];
    const float* Wf2    = (const float*)d_in[10];
    const float* bf2    = (const float*)d_in[11];
    const float* Wf3    = (const float*)d_in[12];
    const float* bf3    = (const float*)d_in[13];
    char* ws = (char*)d_ws;
    f16*   Rb   = (f16*)(ws + OFF_R);
    f16*   Sb   = (f16*)(ws + OFF_S);
    f16*   W2T  = (f16*)(ws + OFF_W2T);
    f16*   Wf1T = (f16*)(ws + OFF_WF1);
    f16*   Wf2T = (f16*)(ws + OFF_WF2);
    f16*   Wf3T = (f16*)(ws + OFF_WF3);
    float* REL  = (float*)(ws + OFF_REL);
    float* AGG  = (float*)(ws + OFF_AGG);
    float* out  = (float*)d_out;

    hipLaunchKernelGGL(k0_prep, dim3(1792), dim3(256), 0, stream,
                       W2, Wf1, Wf2, Wf3, rel, W2T, Wf1T, Wf2T, Wf3T, REL);
    hipLaunchKernelGGL(k1_partials, dim3(252, 32), dim3(256), 0, stream,
                       inputs, W1, b1, Rb, Sb);
    hipLaunchKernelGGL(k2_edge, dim3(4096), dim3(512), 0, stream,
                       Rb, Sb, W2T, b2, REL, AGG);
    hipLaunchKernelGGL(k3_node, dim3(252), dim3(256), 0, stream,
                       inputs, AGG, Wf1T, bf1, Wf2T, bf2, Wf3T, bf3, out);
}

// Round 2
// 657.691 us; speedup vs baseline: 4.6975x; 4.6975x over previous
//
#include <hip/hip_runtime.h>
#include <hip/hip_fp16.h>

typedef _Float16 f16;
typedef _Float16 f16x8 __attribute__((ext_vector_type(8)));
typedef _Float16 f16x4 __attribute__((ext_vector_type(4)));
typedef float    f32x4 __attribute__((ext_vector_type(4)));

#define NB   8
#define NN   32
#define NT   64
#define ND   64
#define NK   4
#define NH   256
#define NSO  256
#define NE   992
#define TOUT 63
#define M1   (NB*TOUT*NN)   // 16128 node-time rows

// ---- workspace layout (bytes) ----
static constexpr size_t SZ_RS   = (size_t)M1 * 1024 * 2;        // 33,030,144 (f16, [m][k*256+h])
static constexpr size_t OFF_R   = 0;
static constexpr size_t OFF_S   = OFF_R + SZ_RS;
static constexpr size_t OFF_W2T = OFF_S + SZ_RS;                // f16 [k][co][h]   524,288
static constexpr size_t OFF_WF1 = OFF_W2T + 4*256*256*2;        // f16 [co][d(320)] 163,840
static constexpr size_t OFF_WF2 = OFF_WF1 + 256*320*2;          // f16 [co][h]      131,072
static constexpr size_t OFF_WF3 = OFF_WF2 + 256*256*2;          // f16 [d][h]        32,768
static constexpr size_t OFF_REL = OFF_WF3 + 64*256*2;           // f32 [b][ns][k][32] 131,072
static constexpr size_t OFF_AGG = OFF_REL + (size_t)NB*NN*NK*32*4; // f32 [m][256]  16,515,072
// W1T (f16 [c(2048)][d(64)], 262,144 B) overlaps the AGG region: k0 writes it,
// k1 consumes it, k2 overwrites AGG afterwards (stream-ordered, safe).
// total = 83,558,400 bytes

// ============================ K0: weight prep ============================
__global__ __launch_bounds__(256) void k0_prep(
    const float* __restrict__ W1, const float* __restrict__ W2,
    const float* __restrict__ Wf1, const float* __restrict__ Wf2,
    const float* __restrict__ Wf3, const float* __restrict__ rel,
    f16* __restrict__ W1T, f16* __restrict__ W2T, f16* __restrict__ Wf1T,
    f16* __restrict__ Wf2T, f16* __restrict__ Wf3T, float* __restrict__ REL)
{
    int id = blockIdx.x * 256 + threadIdx.x;
    if (id < 262144) {                      // W2T[k][co][h] = W2[k][h][co]
        int k = id >> 16, co = (id >> 8) & 255, h = id & 255;
        W2T[id] = (f16)W2[k*65536 + h*256 + co];
    } else if (id < 344064) {               // Wf1T[co][d] = Wf1[d][co], d<320
        int i = id - 262144; int co = i / 320, d = i % 320;
        Wf1T[i] = (f16)Wf1[d*256 + co];
    } else if (id < 409600) {               // Wf2T[co][h] = Wf2[h][co]
        int i = id - 344064; int co = i >> 8, h = i & 255;
        Wf2T[i] = (f16)Wf2[h*256 + co];
    } else if (id < 425984) {               // Wf3T[d][h] = Wf3[h][d], d<64
        int i = id - 409600; int d = i >> 8, h = i & 255;
        Wf3T[i] = (f16)Wf3[h*64 + d];
    } else if (id < 458752) {               // REL[b][ns][k][j], self-edge -> 0
        int i = id - 425984;
        int j = i & 31, k = (i >> 5) & 3, ns = (i >> 7) & 31, b = i >> 12;
        float v = 0.f;
        if (j != ns) v = rel[(b*NE + ns*31 + (j < ns ? j : j - 1))*NK + k];
        REL[i] = v;
    } else {                                // W1T[c][d] = W1[k][dd*64+d][h], c=k*512+dd*256+h
        int i = id - 458752;
        int c = i >> 6, d = i & 63;
        int k = c >> 9, dd = (c >> 8) & 1, h = c & 255;
        W1T[i] = (f16)W1[(k*128 + dd*64 + d)*NH + h];
    }
}

// ============ K1: per-node layer-1 partials R,S (MFMA, f16) ============
// R[m][k*256+h] = x_m @ W1[k][rows 0:64]   (pairs with x_recv in k2)
// S[m][k*256+h] = x_m @ W1[k][rows 64:128] + b1[k]   (pairs with x_send)
__global__ __launch_bounds__(256) void k1_partials(
    const float* __restrict__ inputs, const f16* __restrict__ W1T,
    const float* __restrict__ b1, f16* __restrict__ Rb, f16* __restrict__ Sb)
{
    __shared__ __align__(16) f16 xs[64][72];     // A: 64 rows x 64 d
    __shared__ __align__(16) f16 wl[256][72];    // B: 256 cols x 64 d; reused as out-stage
    int tid = threadIdx.x;
    int w = tid >> 6, lane = tid & 63, ln = lane & 15, q = lane >> 4;
    int m0 = blockIdx.x * 64;

    #pragma unroll
    for (int it = 0; it < 2; ++it) {             // stage x -> f16
        int idx8 = it*256 + tid;
        int m = idx8 >> 3, hs = idx8 & 7;
        int mrow = m0 + m;
        int b = mrow / 2016, r2 = mrow % 2016, t = r2 >> 5, n = r2 & 31;
        const float* px = &inputs[((b*NN + n)*NT + t)*ND + hs*8];
        f32x4 v0 = *(const f32x4*)px, v1 = *(const f32x4*)(px + 4);
        f16x8 o;
        #pragma unroll
        for (int e = 0; e < 4; ++e) { o[e] = (f16)v0[e]; o[e+4] = (f16)v1[e]; }
        *(f16x8*)&xs[m][hs*8] = o;
    }
    const f32x4 z4 = {0.f, 0.f, 0.f, 0.f};
    for (int cc = 0; cc < 8; ++cc) {             // 8 chunks of 256 output cols
        int k = cc >> 1, dd = cc & 1;
        __syncthreads();
        #pragma unroll
        for (int it = 0; it < 8; ++it) {         // stage W1T chunk
            int idx8 = it*256 + tid;
            int co = idx8 >> 3, seg = idx8 & 7;
            *(f16x8*)&wl[co][seg*8] = *(const f16x8*)&W1T[(size_t)(cc*256 + co)*64 + seg*8];
        }
        __syncthreads();
        f32x4 acc[16];
        #pragma unroll
        for (int nt = 0; nt < 16; ++nt) acc[nt] = z4;
        #pragma unroll
        for (int ks = 0; ks < 2; ++ks) {
            f16x8 Af = *(const f16x8*)&xs[w*16 + ln][ks*32 + q*8];
            #pragma unroll
            for (int nt = 0; nt < 16; ++nt) {
                f16x8 Bf = *(const f16x8*)&wl[nt*16 + ln][ks*32 + q*8];
                acc[nt] = __builtin_amdgcn_mfma_f32_16x16x32_f16(Af, Bf, acc[nt], 0, 0, 0);
            }
        }
        __syncthreads();                          // wl now reusable as out staging
        f16* ob = &wl[0][0];                      // 64 rows x 256 cols, stride 264
        #pragma unroll
        for (int nt = 0; nt < 16; ++nt) {
            int co = nt*16 + ln;
            float bias = dd ? b1[k*NH + co] : 0.f;
            #pragma unroll
            for (int r = 0; r < 4; ++r) {
                float v = acc[nt][r] + bias;
                ob[(w*16 + q*4 + r)*264 + co] = (f16)v;
            }
        }
        __syncthreads();
        f16* dst = dd ? Sb : Rb;
        #pragma unroll
        for (int it = 0; it < 8; ++it) {          // 512 B/row coalesced stores
            int idx8 = it*256 + tid;
            int m = idx8 >> 5, seg = idx8 & 31;
            *(f16x8*)&dst[(size_t)(m0 + m)*1024 + k*256 + seg*8] =
                *(const f16x8*)&ob[m*264 + seg*8];
        }
    }
}

// ============ K2: fused edge MLP layer-2 + mixture + sender-aggregate ============
// wg = (b, ns, tc): 4 time steps x 32 padded edges (M=128 rows), 512 threads.
// waves: 2 M-groups x 4 N-groups; per wave 4 Mtiles x 4 Ntiles (acc 64 VGPR/lane).
__global__ __launch_bounds__(512, 4) void k2_edge(
    const f16* __restrict__ Rb, const f16* __restrict__ Sb,
    const f16* __restrict__ W2T, const float* __restrict__ b2,
    const float* __restrict__ REL, float* __restrict__ AGG)
{
    __shared__ __align__(16) f16 h1c[128][72];   // h1 chunk (64 h), +8 pad
    __shared__ __align__(16) f16 w2c[256][72];   // W2^T chunk [co][64 h]
    __shared__ __align__(16) float agg_s[4][256];
    int tid = threadIdx.x;
    int blk = blockIdx.x;
    int ns = blk & 31, tcv = (blk >> 5) & 15, b = blk >> 9;
    int w = tid >> 6, lane = tid & 63, ln = lane & 15, q = lane >> 4;
    int mg = w >> 2, ng = w & 3;

    agg_s[tid >> 8][tid & 255] = 0.f;
    agg_s[2 + (tid >> 8)][tid & 255] = 0.f;

    const f32x4 z4 = {0.f, 0.f, 0.f, 0.f};
    f32x4 acc[4][4];
    for (int k = 0; k < 4; ++k) {
        #pragma unroll
        for (int mt = 0; mt < 4; ++mt)
            #pragma unroll
            for (int nt = 0; nt < 4; ++nt) acc[mt][nt] = z4;

        for (int hc = 0; hc < 4; ++hc) {
            __syncthreads();
            // h1 chunk: relu(R[recv] + S[send]) for 128 rows x 64 h
            #pragma unroll
            for (int it = 0; it < 2; ++it) {
                int idx8 = it*512 + tid;
                int m = idx8 >> 3, seg = idx8 & 7, h = hc*64 + seg*8;
                int t = tcv*4 + (m >> 5); if (t > 62) t = 62;  // clamp pad-t (never stored)
                int j = m & 31;
                size_t base = (size_t)(b*TOUT + t) * NN;
                f16x8 r8 = *(const f16x8*)&Rb[(base + j)*1024 + k*256 + h];
                f16x8 s8 = *(const f16x8*)&Sb[(base + ns)*1024 + k*256 + h];
                f16x8 v;
                #pragma unroll
                for (int e = 0; e < 8; ++e) {
                    f16 x = r8[e] + s8[e];
                    v[e] = x > (f16)0 ? x : (f16)0;
                }
                *(f16x8*)&h1c[m][seg*8] = v;
            }
            // W2^T chunk
            #pragma unroll
            for (int it = 0; it < 4; ++it) {
                int idx8 = it*512 + tid;
                int co = idx8 >> 3, seg = idx8 & 7;
                *(f16x8*)&w2c[co][seg*8] =
                    *(const f16x8*)&W2T[(size_t)(k*256 + co)*256 + hc*64 + seg*8];
            }
            __syncthreads();
            #pragma unroll
            for (int ks = 0; ks < 2; ++ks) {
                f16x8 A[4];
                #pragma unroll
                for (int mt = 0; mt < 4; ++mt)
                    A[mt] = *(const f16x8*)&h1c[mg*64 + mt*16 + ln][ks*32 + q*8];
                #pragma unroll
                for (int nt = 0; nt < 4; ++nt) {
                    f16x8 Bf = *(const f16x8*)&w2c[ng*64 + nt*16 + ln][ks*32 + q*8];
                    #pragma unroll
                    for (int mt = 0; mt < 4; ++mt)
                        acc[mt][nt] = __builtin_amdgcn_mfma_f32_16x16x32_f16(
                            A[mt], Bf, acc[mt][nt], 0, 0, 0);
                }
            }
        }
        // epilogue for mixture k: bias+relu, scale by rel, reduce rows -> agg
        #pragma unroll
        for (int mt = 0; mt < 4; ++mt) {
            int tl = mg*2 + (mt >> 1);
            int e0 = (mt & 1)*16 + q*4;
            f32x4 relv = *(const f32x4*)&REL[((b*NN + ns)*NK + k)*32 + e0];
            #pragma unroll
            for (int nt = 0; nt < 4; ++nt) {
                int co = ng*64 + nt*16 + ln;
                float bias = b2[k*NSO + co];
                float s = 0.f;
                #pragma unroll
                for (int r = 0; r < 4; ++r) {
                    float v = acc[mt][nt][r] + bias;
                    v = v > 0.f ? v : 0.f;
                    s += v * relv[r];
                }
                s += __shfl_xor(s, 16);
                s += __shfl_xor(s, 32);
                if (lane < 16) agg_s[tl][ng*64 + nt*16 + lane] += s;
            }
        }
    }
    __syncthreads();
    #pragma unroll
    for (int it = 0; it < 2; ++it) {
        int idx = it*512 + tid;
        int tl = idx >> 8, co = idx & 255;
        int t = tcv*4 + tl;
        if (t < 63)
            AGG[((size_t)(b*TOUT + t)*NN + ns)*NSO + co] = agg_s[tl][co];
    }
}

// ============ K3: node MLP (320->256->256->64) + residual ============
__global__ __launch_bounds__(256) void k3_node(
    const float* __restrict__ inputs, const float* __restrict__ AGG,
    const f16* __restrict__ Wf1T, const float* __restrict__ bf1,
    const f16* __restrict__ Wf2T, const float* __restrict__ bf2,
    const f16* __restrict__ Wf3T, const float* __restrict__ bf3,
    float* __restrict__ out)
{
    __shared__ __align__(16) f16 aug[64][328];   // [x(64) | agg(256)] + pad
    __shared__ __align__(16) f16 p1[64][264];
    __shared__ __align__(16) f16 wl[256][72];
    int tid = threadIdx.x;
    int w = tid >> 6, lane = tid & 63, ln = lane & 15, q = lane >> 4;
    int m0 = blockIdx.x * 64;

    for (int it = 0; it < 10; ++it) {       // stage aug
        int s = it*256 + tid;
        if (s < 512) {
            int m = s >> 3, hs = s & 7;
            int mrow = m0 + m;
            int b = mrow / 2016, r2 = mrow % 2016, t = r2 >> 5, n = r2 & 31;
            const float* px = &inputs[((b*NN + n)*NT + t)*ND + hs*8];
            f32x4 v0 = *(const f32x4*)px, v1 = *(const f32x4*)(px + 4);
            f16x8 o;
            #pragma unroll
            for (int e = 0; e < 4; ++e) { o[e] = (f16)v0[e]; o[e+4] = (f16)v1[e]; }
            *(f16x8*)&aug[m][hs*8] = o;
        } else {
            int s2 = s - 512;
            int m = s2 >> 5, hs = s2 & 31;
            const float* pa = &AGG[(size_t)(m0 + m)*NSO + hs*8];
            f32x4 v0 = *(const f32x4*)pa, v1 = *(const f32x4*)(pa + 4);
            f16x8 o;
            #pragma unroll
            for (int e = 0; e < 4; ++e) { o[e] = (f16)v0[e]; o[e+4] = (f16)v1[e]; }
            *(f16x8*)&aug[m][64 + hs*8] = o;
        }
    }
    const f32x4 z4 = {0.f, 0.f, 0.f, 0.f};
    // ---- layer 1: K=320 ----
    f32x4 acc1[16];
    #pragma unroll
    for (int nt = 0; nt < 16; ++nt) acc1[nt] = z4;
    for (int hc = 0; hc < 5; ++hc) {
        __syncthreads();
        #pragma unroll
        for (int it = 0; it < 8; ++it) {
            int idx8 = it*256 + tid;
            int co = idx8 >> 3, seg = idx8 & 7;
            *(f16x8*)&wl[co][seg*8] = *(const f16x8*)&Wf1T[co*320 + hc*64 + seg*8];
        }
        __syncthreads();
        #pragma unroll
        for (int ks = 0; ks < 2; ++ks) {
            f16x8 Af = *(const f16x8*)&aug[w*16 + ln][hc*64 + ks*32 + q*8];
            #pragma unroll
            for (int nt = 0; nt < 16; ++nt) {
                f16x8 Bf = *(const f16x8*)&wl[nt*16 + ln][ks*32 + q*8];
                acc1[nt] = __builtin_amdgcn_mfma_f32_16x16x32_f16(Af, Bf, acc1[nt], 0, 0, 0);
            }
        }
    }
    #pragma unroll
    for (int nt = 0; nt < 16; ++nt) {
        int co = nt*16 + ln;
        float bias = bf1[co];
        #pragma unroll
        for (int r = 0; r < 4; ++r) {
            float v = acc1[nt][r] + bias; v = v > 0.f ? v : 0.f;
            p1[w*16 + q*4 + r][co] = (f16)v;
        }
    }
    // ---- layer 2: K=256 ----
    f32x4 acc2[16];
    #pragma unroll
    for (int nt = 0; nt < 16; ++nt) acc2[nt] = z4;
    for (int hc = 0; hc < 4; ++hc) {
        __syncthreads();
        #pragma unroll
        for (int it = 0; it < 8; ++it) {
            int idx8 = it*256 + tid;
            int co = idx8 >> 3, seg = idx8 & 7;
            *(f16x8*)&wl[co][seg*8] = *(const f16x8*)&Wf2T[co*256 + hc*64 + seg*8];
        }
        __syncthreads();
        #pragma unroll
        for (int ks = 0; ks < 2; ++ks) {
            f16x8 Af = *(const f16x8*)&p1[w*16 + ln][hc*64 + ks*32 + q*8];
            #pragma unroll
            for (int nt = 0; nt < 16; ++nt) {
                f16x8 Bf = *(const f16x8*)&wl[nt*16 + ln][ks*32 + q*8];
                acc2[nt] = __builtin_amdgcn_mfma_f32_16x16x32_f16(Af, Bf, acc2[nt], 0, 0, 0);
            }
        }
    }
    f16* p2 = &aug[0][0];    // reuse aug storage, stride 264
    #pragma unroll
    for (int nt = 0; nt < 16; ++nt) {
        int co = nt*16 + ln;
        float bias = bf2[co];
        #pragma unroll
        for (int r = 0; r < 4; ++r) {
            float v = acc2[nt][r] + bias; v = v > 0.f ? v : 0.f;
            p2[(w*16 + q*4 + r)*264 + co] = (f16)v;
        }
    }
    __syncthreads();
    // ---- layer 3: K=256, N=64 ----
    f16* w3 = &wl[0][0];     // reuse wl storage, stride 264
    #pragma unroll
    for (int it = 0; it < 8; ++it) {
        int idx8 = it*256 + tid;
        int d = idx8 >> 5, seg = idx8 & 31;
        *(f16x8*)&w3[d*264 + seg*8] = *(const f16x8*)&Wf3T[d*256 + seg*8];
    }
    __syncthreads();
    f32x4 acc3[4];
    #pragma unroll
    for (int nt = 0; nt < 4; ++nt) acc3[nt] = z4;
    #pragma unroll
    for (int ks = 0; ks < 8; ++ks) {
        f16x8 Af = *(const f16x8*)&p2[(w*16 + ln)*264 + ks*32 + q*8];
        #pragma unroll
        for (int nt = 0; nt < 4; ++nt) {
            f16x8 Bf = *(const f16x8*)&w3[(nt*16 + ln)*264 + ks*32 + q*8];
            acc3[nt] = __builtin_amdgcn_mfma_f32_16x16x32_f16(Af, Bf, acc3[nt], 0, 0, 0);
        }
    }
    #pragma unroll
    for (int nt = 0; nt < 4; ++nt) {
        int d = nt*16 + ln;
        float bias = bf3[d];
        #pragma unroll
        for (int r = 0; r < 4; ++r) {
            int mrow = m0 + w*16 + q*4 + r;
            int b = mrow / 2016, r2 = mrow % 2016, t = r2 >> 5, n = r2 & 31;
            float xv = inputs[((b*NN + n)*NT + t)*ND + d];
            out[((size_t)(b*NN + n)*TOUT + t)*ND + d] = acc3[nt][r] + bias + xv;
        }
    }
}

extern "C" void kernel_launch(void* const* d_in, const int* in_sizes, int n_in,
                              void* d_out, int out_size, void* d_ws, size_t ws_size,
                              hipStream_t stream)
{
    const float* inputs = (const float*)d_in[0];
    const float* rel    = (const float*)d_in[1];
    const float* W1     = (const float*)d_in[4];
    const float* b1     = (const float*)d_in[5];
    const float* W2     = (const float*)d_in[6];
    const float* b2     = (const float*)d_in[7];
    const float* Wf1    = (const float*)d_in[8];
    const float* bf1    = (const float*)d_in[9];
    const float* Wf2    = (const float*)d_in[10];
    const float* bf2    = (const float*)d_in[11];
    const float* Wf3    = (const float*)d_in[12];
    const float* bf3    = (const float*)d_in[13];
    char* ws = (char*)d_ws;
    f16*   Rb   = (f16*)(ws + OFF_R);
    f16*   Sb   = (f16*)(ws + OFF_S);
    f16*   W2T  = (f16*)(ws + OFF_W2T);
    f16*   Wf1T = (f16*)(ws + OFF_WF1);
    f16*   Wf2T = (f16*)(ws + OFF_WF2);
    f16*   Wf3T = (f16*)(ws + OFF_WF3);
    float* REL  = (float*)(ws + OFF_REL);
    float* AGG  = (float*)(ws + OFF_AGG);
    f16*   W1T  = (f16*)(ws + OFF_AGG);   // overlaps AGG; consumed before k2 writes AGG
    float* out  = (float*)d_out;

    hipLaunchKernelGGL(k0_prep, dim3(2304), dim3(256), 0, stream,
                       W1, W2, Wf1, Wf2, Wf3, rel, W1T, W2T, Wf1T, Wf2T, Wf3T, REL);
    hipLaunchKernelGGL(k1_partials, dim3(252), dim3(256), 0, stream,
                       inputs, W1T, b1, Rb, Sb);
    hipLaunchKernelGGL(k2_edge, dim3(4096), dim3(512), 0, stream,
                       Rb, Sb, W2T, b2, REL, AGG);
    hipLaunchKernelGGL(k3_node, dim3(252), dim3(256), 0, stream,
                       inputs, AGG, Wf1T, bf1, Wf2T, bf2, Wf3T, bf3, out);
}